// Round 3
// baseline (63.318 us; speedup 1.0000x reference)
//
#include <hip/hip_runtime.h>
#include <math.h>

#define KSEL 32
#define DDIM 256
#define SDIM 256
#define SM1  255
#define EPSN 1e-12f

__global__ __launch_bounds__(512) void matching_reducer_kernel(
    const float* __restrict__ nse,   // (B,H,S,D) news_selection_embedding
    const float* __restrict__ ne,    // (B,H,S,D) news_embedding
    const float* __restrict__ ur,    // (B,1,D)   user_repr
    const float* __restrict__ am,    // (B,H,S)   his_attn_mask
    const int*   __restrict__ rm,    // (B,H,S)   his_refined_mask
    const float* __restrict__ seg,   // (H,1,D)   segment_embedding
    float* __restrict__ out_terms,   // (B,H*K,D)
    float* __restrict__ out_mask,    // (B,H*K)
    float* __restrict__ out_kid,     // (B,H*K)   indices as float
    int H)
{
    const int bh   = blockIdx.x;
    const int b    = bh / H;
    const int h    = bh % H;
    const int tid  = threadIdx.x;
    const int lane = tid & 63;
    const int wave = tid >> 6;   // 0..7
    const int g    = tid >> 4;   // 32 groups of 16 lanes
    const int t    = tid & 15;

    __shared__ float  s_scores[256];
    __shared__ int    s_rows[256];
    __shared__ int    s_wbase[8];
    __shared__ int    s_nv;
    __shared__ float  s_sk[KSEL];
    __shared__ int    s_kid[KSEL];
    __shared__ float  s_w[KSEL];
    __shared__ float4 s_seg[64];

    if (tid < 64) {
        s_seg[tid] = reinterpret_cast<const float4*>(seg + (size_t)h * DDIM)[tid];
    }
    if (tid < 256) s_scores[tid] = -INFINITY;

    // ---- validity + compaction (rows live in tid 0..254, waves 0..3) ----
    const int* rmb = rm + (size_t)bh * SDIM + 1;
    const bool valid = (tid < SM1) && ((rmb[tid] != 0) || (tid < KSEL));
    const unsigned long long ball = __ballot(valid);
    if (lane == 0) s_wbase[wave] = __popcll(ball);

    // ---- q fragments: lane t holds q float4s {t, t+16, t+32, t+48} ----
    const float4* qv = reinterpret_cast<const float4*>(ur + (size_t)b * DDIM);
    float4 qf[4];
    #pragma unroll
    for (int j = 0; j < 4; ++j) qf[j] = qv[t + 16 * j];
    float qq = 0.f;
    #pragma unroll
    for (int j = 0; j < 4; ++j)
        qq += qf[j].x * qf[j].x + qf[j].y * qf[j].y + qf[j].z * qf[j].z + qf[j].w * qf[j].w;
    #pragma unroll
    for (int o = 8; o > 0; o >>= 1) qq += __shfl_xor(qq, o, 16);
    const float inv_q = 1.0f / fmaxf(sqrtf(qq), EPSN);

    __syncthreads();
    if (tid == 0) {
        int acc = 0;
        #pragma unroll
        for (int w2 = 0; w2 < 8; ++w2) { int c = s_wbase[w2]; s_wbase[w2] = acc; acc += c; }
        s_nv = acc;
    }
    __syncthreads();
    if (valid) {
        const int off = __popcll(ball & ((1ull << lane) - 1ull));
        s_rows[s_wbase[wave] + off] = tid;
    }
    __syncthreads();

    // ---- score pass over valid rows; group g owns residues g (mod 32),
    //      2 rows in flight per group ----
    const int nv = s_nv;
    const float* selb = nse + ((size_t)bh * SDIM + 1) * DDIM;
    for (int i = g; i < nv; i += 64) {
        const int  rowA = s_rows[i];
        const bool hasB = (i + 32) < nv;
        const int  rowB = hasB ? s_rows[i + 32] : rowA;
        const float4* xa = reinterpret_cast<const float4*>(selb + (size_t)rowA * DDIM);
        const float4* xb = reinterpret_cast<const float4*>(selb + (size_t)rowB * DDIM);
        float4 va[4], vb[4];
        #pragma unroll
        for (int j = 0; j < 4; ++j) { va[j] = xa[t + 16 * j]; vb[j] = xb[t + 16 * j]; }
        float dotA = 0.f, ssA = 0.f, dotB = 0.f, ssB = 0.f;
        #pragma unroll
        for (int j = 0; j < 4; ++j) {
            dotA += va[j].x * qf[j].x + va[j].y * qf[j].y + va[j].z * qf[j].z + va[j].w * qf[j].w;
            ssA  += va[j].x * va[j].x + va[j].y * va[j].y + va[j].z * va[j].z + va[j].w * va[j].w;
            dotB += vb[j].x * qf[j].x + vb[j].y * qf[j].y + vb[j].z * qf[j].z + vb[j].w * qf[j].w;
            ssB  += vb[j].x * vb[j].x + vb[j].y * vb[j].y + vb[j].z * vb[j].z + vb[j].w * vb[j].w;
        }
        #pragma unroll
        for (int o = 8; o > 0; o >>= 1) {
            dotA += __shfl_xor(dotA, o, 16);
            ssA  += __shfl_xor(ssA,  o, 16);
            dotB += __shfl_xor(dotB, o, 16);
            ssB  += __shfl_xor(ssB,  o, 16);
        }
        if (t == 0) {
            s_scores[rowA] = dotA * inv_q / fmaxf(sqrtf(ssA), EPSN);
            if (hasB) s_scores[rowB] = dotB * inv_q / fmaxf(sqrtf(ssB), EPSN);
        }
    }
    __syncthreads();

    // ---- top-K (wave 0): iterative argmax, tie -> smallest index ----
    if (wave == 0) {
        float v[4];
        #pragma unroll
        for (int j = 0; j < 4; ++j) v[j] = s_scores[lane + 64 * j];
        for (int k = 0; k < KSEL; ++k) {
            float bv = v[0];
            int   bi = lane;
            #pragma unroll
            for (int j = 1; j < 4; ++j) {
                const int idx = lane + 64 * j;
                if (v[j] > bv || (v[j] == bv && idx < bi)) { bv = v[j]; bi = idx; }
            }
            #pragma unroll
            for (int o = 32; o > 0; o >>= 1) {
                float ov = __shfl_xor(bv, o, 64);
                int   oi = __shfl_xor(bi, o, 64);
                if (ov > bv || (ov == bv && oi < bi)) { bv = ov; bi = oi; }
            }
            if (lane == 0) { s_sk[k] = bv; s_kid[k] = bi; }
            if ((bi & 63) == lane) v[bi >> 6] = -INFINITY;
        }
        const float m = s_sk[0];
        float e = (lane < KSEL) ? expf(s_sk[lane] - m) : 0.0f;
        float sum = e;
        #pragma unroll
        for (int o = 32; o > 0; o >>= 1) sum += __shfl_xor(sum, o, 64);
        if (lane < KSEL) s_w[lane] = e / sum;
    }
    __syncthreads();

    // ---- output: each wave writes one full row per pass (4 passes) ----
    const float* txtb = ne + ((size_t)bh * SDIM + 1) * DDIM;
    float* outb = out_terms + (size_t)bh * KSEL * DDIM;
    #pragma unroll
    for (int p = 0; p < 4; ++p) {
        const int k    = p * 8 + wave;
        const int kidx = s_kid[k];
        const float wk = s_w[k];
        float4 x  = reinterpret_cast<const float4*>(txtb + (size_t)kidx * DDIM)[lane];
        float4 sg = s_seg[lane];
        float4 r;
        r.x = x.x * wk + sg.x;
        r.y = x.y * wk + sg.y;
        r.z = x.z * wk + sg.z;
        r.w = x.w * wk + sg.w;
        reinterpret_cast<float4*>(outb + (size_t)k * DDIM)[lane] = r;
    }
    if (tid < KSEL) {
        const int kidx = s_kid[tid];
        out_mask[(size_t)bh * KSEL + tid] = am[(size_t)bh * SDIM + 1 + kidx];
        out_kid [(size_t)bh * KSEL + tid] = (float)kidx;
    }
}

extern "C" void kernel_launch(void* const* d_in, const int* in_sizes, int n_in,
                              void* d_out, int out_size, void* d_ws, size_t ws_size,
                              hipStream_t stream) {
    const float* nse = (const float*)d_in[0];
    const float* ne  = (const float*)d_in[1];
    const float* ur  = (const float*)d_in[2];
    const float* am  = (const float*)d_in[4];
    const int*   rm  = (const int*)  d_in[5];
    const float* seg = (const float*)d_in[6];

    const int B = in_sizes[2] / DDIM;
    const int H = in_sizes[6] / DDIM;

    float* out = (float*)d_out;
    const size_t n_terms = (size_t)B * H * KSEL * DDIM;
    const size_t n_mask  = (size_t)B * H * KSEL;

    matching_reducer_kernel<<<dim3(B * H), dim3(512), 0, stream>>>(
        nse, ne, ur, am, rm, seg,
        out, out + n_terms, out + n_terms + n_mask, H);
}

// Round 4
// 49.003 us; speedup vs baseline: 1.2921x; 1.2921x over previous
//
#include <hip/hip_runtime.h>
#include <math.h>

#define KSEL 32
#define DDIM 256
#define SDIM 256
#define SM1  255
#define EPSN 1e-12f

__global__ __launch_bounds__(256) void matching_reducer_kernel(
    const float* __restrict__ nse,   // (B,H,S,D) news_selection_embedding
    const float* __restrict__ ne,    // (B,H,S,D) news_embedding
    const float* __restrict__ ur,    // (B,1,D)   user_repr
    const float* __restrict__ am,    // (B,H,S)   his_attn_mask
    const int*   __restrict__ rm,    // (B,H,S)   his_refined_mask
    const float* __restrict__ seg,   // (H,1,D)   segment_embedding
    float* __restrict__ out_terms,   // (B,H*K,D)
    float* __restrict__ out_mask,    // (B,H*K)
    float* __restrict__ out_kid,     // (B,H*K)   indices as float
    int H)
{
    const int bh   = blockIdx.x;
    const int b    = bh / H;
    const int h    = bh % H;
    const int tid  = threadIdx.x;
    const int lane = tid & 63;
    const int wave = tid >> 6;   // 0..3
    const int g    = tid >> 4;   // 16 groups of 16 lanes
    const int t    = tid & 15;

    __shared__ float  s_dot[256][17];   // per-row lane partials (pad 17: conflict-free)
    __shared__ float  s_ss[256][17];
    __shared__ float  s_scores[256];
    __shared__ int    s_rows[256];
    __shared__ int    s_wbase[4];
    __shared__ int    s_nv;
    __shared__ float  s_sk[KSEL];
    __shared__ int    s_kid[KSEL];
    __shared__ float  s_w[KSEL];
    __shared__ float4 s_seg[64];

    if (tid < 64) {
        s_seg[tid] = reinterpret_cast<const float4*>(seg + (size_t)h * DDIM)[tid];
    }
    s_scores[tid] = -INFINITY;

    // ---- validity + compaction: valid = refined_mask!=0 OR first-K slot ----
    const int* rmb = rm + (size_t)bh * SDIM + 1;
    const bool valid = (tid < SM1) && ((rmb[tid] != 0) || (tid < KSEL));
    const unsigned long long ball = __ballot(valid);
    if (lane == 0) s_wbase[wave] = __popcll(ball);

    // ---- q fragments: lane t holds q float4s {t, t+16, t+32, t+48} ----
    const float4* qv = reinterpret_cast<const float4*>(ur + (size_t)b * DDIM);
    float4 qf[4];
    #pragma unroll
    for (int j = 0; j < 4; ++j) qf[j] = qv[t + 16 * j];
    float qq = 0.f;
    #pragma unroll
    for (int j = 0; j < 4; ++j)
        qq += qf[j].x * qf[j].x + qf[j].y * qf[j].y + qf[j].z * qf[j].z + qf[j].w * qf[j].w;
    #pragma unroll
    for (int o = 8; o > 0; o >>= 1) qq += __shfl_xor(qq, o, 16);
    const float inv_q = 1.0f / fmaxf(sqrtf(qq), EPSN);

    __syncthreads();
    if (tid == 0) {
        int acc = 0;
        #pragma unroll
        for (int w2 = 0; w2 < 4; ++w2) { int c = s_wbase[w2]; s_wbase[w2] = acc; acc += c; }
        s_nv = acc;
    }
    __syncthreads();
    if (valid) {
        const int off = __popcll(ball & ((1ull << lane) - 1ull));
        s_rows[s_wbase[wave] + off] = tid;
    }
    __syncthreads();

    // ---- score pass: NO cross-lane ops in the loop — pure load+FMA+LDS
    //      store, so loads pipeline deeply across iterations ----
    const int nv = s_nv;
    const float* selb = nse + ((size_t)bh * SDIM + 1) * DDIM;
    for (int i = g; i < nv; i += 32) {
        const int  rowA = s_rows[i];
        const bool hasB = (i + 16) < nv;
        const int  rowB = hasB ? s_rows[i + 16] : rowA;
        const float4* xa = reinterpret_cast<const float4*>(selb + (size_t)rowA * DDIM);
        const float4* xb = reinterpret_cast<const float4*>(selb + (size_t)rowB * DDIM);
        float4 va[4], vb[4];
        #pragma unroll
        for (int j = 0; j < 4; ++j) { va[j] = xa[t + 16 * j]; vb[j] = xb[t + 16 * j]; }
        float dotA = 0.f, ssA = 0.f, dotB = 0.f, ssB = 0.f;
        #pragma unroll
        for (int j = 0; j < 4; ++j) {
            dotA += va[j].x * qf[j].x + va[j].y * qf[j].y + va[j].z * qf[j].z + va[j].w * qf[j].w;
            ssA  += va[j].x * va[j].x + va[j].y * va[j].y + va[j].z * va[j].z + va[j].w * va[j].w;
            dotB += vb[j].x * qf[j].x + vb[j].y * qf[j].y + vb[j].z * qf[j].z + vb[j].w * qf[j].w;
            ssB  += vb[j].x * vb[j].x + vb[j].y * vb[j].y + vb[j].z * vb[j].z + vb[j].w * vb[j].w;
        }
        s_dot[rowA][t] = dotA;
        s_ss [rowA][t] = ssA;
        if (hasB) { s_dot[rowB][t] = dotB; s_ss[rowB][t] = ssB; }
    }
    __syncthreads();

    // ---- per-row partial reduce: thread tid owns row tid ----
    if (valid) {
        float dv = 0.f, sv = 0.f;
        #pragma unroll
        for (int j = 0; j < 16; ++j) { dv += s_dot[tid][j]; sv += s_ss[tid][j]; }
        s_scores[tid] = dv * inv_q / fmaxf(sqrtf(sv), EPSN);
    }
    __syncthreads();

    // ---- top-K (wave 0): iterative argmax, tie -> smallest index ----
    if (wave == 0) {
        float v[4];
        #pragma unroll
        for (int j = 0; j < 4; ++j) v[j] = s_scores[lane + 64 * j];
        for (int k = 0; k < KSEL; ++k) {
            float bv = v[0];
            int   bi = lane;
            #pragma unroll
            for (int j = 1; j < 4; ++j) {
                const int idx = lane + 64 * j;
                if (v[j] > bv || (v[j] == bv && idx < bi)) { bv = v[j]; bi = idx; }
            }
            #pragma unroll
            for (int o = 32; o > 0; o >>= 1) {
                float ov = __shfl_xor(bv, o, 64);
                int   oi = __shfl_xor(bi, o, 64);
                if (ov > bv || (ov == bv && oi < bi)) { bv = ov; bi = oi; }
            }
            if (lane == 0) { s_sk[k] = bv; s_kid[k] = bi; }
            if ((bi & 63) == lane) v[bi >> 6] = -INFINITY;
        }
        const float m = s_sk[0];
        float e = (lane < KSEL) ? expf(s_sk[lane] - m) : 0.0f;
        float sum = e;
        #pragma unroll
        for (int o = 32; o > 0; o >>= 1) sum += __shfl_xor(sum, o, 64);
        if (lane < KSEL) s_w[lane] = e / sum;
    }
    __syncthreads();

    // ---- output: gather txt rows, scale by w, add segment embedding ----
    const float* txtb = ne + ((size_t)bh * SDIM + 1) * DDIM;
    float* outb = out_terms + (size_t)bh * KSEL * DDIM;
    const int d4 = tid & 63;
    #pragma unroll
    for (int p = 0; p < 8; ++p) {
        const int k    = p * 4 + (tid >> 6);
        const int kidx = s_kid[k];
        const float wk = s_w[k];
        float4 x  = reinterpret_cast<const float4*>(txtb + (size_t)kidx * DDIM)[d4];
        float4 sg = s_seg[d4];
        float4 r;
        r.x = x.x * wk + sg.x;
        r.y = x.y * wk + sg.y;
        r.z = x.z * wk + sg.z;
        r.w = x.w * wk + sg.w;
        reinterpret_cast<float4*>(outb + (size_t)k * DDIM)[d4] = r;
    }
    if (tid < KSEL) {
        const int kidx = s_kid[tid];
        out_mask[(size_t)bh * KSEL + tid] = am[(size_t)bh * SDIM + 1 + kidx];
        out_kid [(size_t)bh * KSEL + tid] = (float)kidx;
    }
}

extern "C" void kernel_launch(void* const* d_in, const int* in_sizes, int n_in,
                              void* d_out, int out_size, void* d_ws, size_t ws_size,
                              hipStream_t stream) {
    const float* nse = (const float*)d_in[0];
    const float* ne  = (const float*)d_in[1];
    const float* ur  = (const float*)d_in[2];
    const float* am  = (const float*)d_in[4];
    const int*   rm  = (const int*)  d_in[5];
    const float* seg = (const float*)d_in[6];

    const int B = in_sizes[2] / DDIM;
    const int H = in_sizes[6] / DDIM;

    float* out = (float*)d_out;
    const size_t n_terms = (size_t)B * H * KSEL * DDIM;
    const size_t n_mask  = (size_t)B * H * KSEL;

    matching_reducer_kernel<<<dim3(B * H), dim3(256), 0, stream>>>(
        nse, ne, ur, am, rm, seg,
        out, out + n_terms, out + n_terms + n_mask, H);
}

// Round 5
// 33.139 us; speedup vs baseline: 1.9107x; 1.4787x over previous
//
#include <hip/hip_runtime.h>
#include <math.h>

#define KSEL 32
#define DDIM 256
#define SDIM 256
#define SM1  255
#define EPSN 1e-12f

__global__ __launch_bounds__(256) void matching_reducer_kernel(
    const float* __restrict__ nse,   // (B,H,S,D) news_selection_embedding
    const float* __restrict__ ne,    // (B,H,S,D) news_embedding
    const float* __restrict__ ur,    // (B,1,D)   user_repr
    const float* __restrict__ am,    // (B,H,S)   his_attn_mask
    const int*   __restrict__ rm,    // (B,H,S)   his_refined_mask
    const float* __restrict__ seg,   // (H,1,D)   segment_embedding
    float* __restrict__ out_terms,   // (B,H*K,D)
    float* __restrict__ out_mask,    // (B,H*K)
    float* __restrict__ out_kid,     // (B,H*K)   indices as float
    int H)
{
    const int bh   = blockIdx.x;
    const int b    = bh / H;
    const int h    = bh % H;
    const int tid  = threadIdx.x;
    const int lane = tid & 63;
    const int wave = tid >> 6;   // 0..3
    const int g    = tid >> 4;   // 16 groups of 16 lanes
    const int t    = tid & 15;

    __shared__ float  s_dot[256][17];   // per-row lane partials (pad 17)
    __shared__ float  s_ss[256][17];
    __shared__ float  s_scores[256];
    __shared__ int    s_rows[256];
    __shared__ unsigned long long s_key[256];
    __shared__ int    s_wbase[4];
    __shared__ int    s_nv;
    __shared__ int    s_kid[KSEL];
    __shared__ float  s_w[KSEL];
    __shared__ float4 s_seg[64];

    if (tid < 64) {
        s_seg[tid] = reinterpret_cast<const float4*>(seg + (size_t)h * DDIM)[tid];
    }
    s_scores[tid] = -INFINITY;

    // ---- validity + compaction: valid = refined_mask!=0 OR first-K slot ----
    const int* rmb = rm + (size_t)bh * SDIM + 1;
    const bool valid = (tid < SM1) && ((rmb[tid] != 0) || (tid < KSEL));
    const unsigned long long ball = __ballot(valid);
    if (lane == 0) s_wbase[wave] = __popcll(ball);

    // ---- q fragments: lane t holds q float4s {t, t+16, t+32, t+48} ----
    const float4* qv = reinterpret_cast<const float4*>(ur + (size_t)b * DDIM);
    float4 qf[4];
    #pragma unroll
    for (int j = 0; j < 4; ++j) qf[j] = qv[t + 16 * j];
    float qq = 0.f;
    #pragma unroll
    for (int j = 0; j < 4; ++j)
        qq += qf[j].x * qf[j].x + qf[j].y * qf[j].y + qf[j].z * qf[j].z + qf[j].w * qf[j].w;
    #pragma unroll
    for (int o = 8; o > 0; o >>= 1) qq += __shfl_xor(qq, o, 16);
    const float inv_q = 1.0f / fmaxf(sqrtf(qq), EPSN);

    __syncthreads();
    if (tid == 0) {
        int acc = 0;
        #pragma unroll
        for (int w2 = 0; w2 < 4; ++w2) { int c = s_wbase[w2]; s_wbase[w2] = acc; acc += c; }
        s_nv = acc;
    }
    __syncthreads();
    if (valid) {
        const int off = __popcll(ball & ((1ull << lane) - 1ull));
        s_rows[s_wbase[wave] + off] = tid;
    }
    __syncthreads();

    // ---- score pass: pure load+FMA+LDS store, deep load pipelining ----
    const int nv = s_nv;
    const float* selb = nse + ((size_t)bh * SDIM + 1) * DDIM;
    for (int i = g; i < nv; i += 32) {
        const int  rowA = s_rows[i];
        const bool hasB = (i + 16) < nv;
        const int  rowB = hasB ? s_rows[i + 16] : rowA;
        const float4* xa = reinterpret_cast<const float4*>(selb + (size_t)rowA * DDIM);
        const float4* xb = reinterpret_cast<const float4*>(selb + (size_t)rowB * DDIM);
        float4 va[4], vb[4];
        #pragma unroll
        for (int j = 0; j < 4; ++j) { va[j] = xa[t + 16 * j]; vb[j] = xb[t + 16 * j]; }
        float dotA = 0.f, ssA = 0.f, dotB = 0.f, ssB = 0.f;
        #pragma unroll
        for (int j = 0; j < 4; ++j) {
            dotA += va[j].x * qf[j].x + va[j].y * qf[j].y + va[j].z * qf[j].z + va[j].w * qf[j].w;
            ssA  += va[j].x * va[j].x + va[j].y * va[j].y + va[j].z * va[j].z + va[j].w * va[j].w;
            dotB += vb[j].x * qf[j].x + vb[j].y * qf[j].y + vb[j].z * qf[j].z + vb[j].w * qf[j].w;
            ssB  += vb[j].x * vb[j].x + vb[j].y * vb[j].y + vb[j].z * vb[j].z + vb[j].w * vb[j].w;
        }
        s_dot[rowA][t] = dotA;
        s_ss [rowA][t] = ssA;
        if (hasB) { s_dot[rowB][t] = dotB; s_ss[rowB][t] = ssB; }
    }
    __syncthreads();

    // ---- per-row partial reduce: thread tid owns row tid ----
    if (valid) {
        float dv = 0.f, sv = 0.f;
        #pragma unroll
        for (int j = 0; j < 16; ++j) { dv += s_dot[tid][j]; sv += s_ss[tid][j]; }
        s_scores[tid] = dv * inv_q / fmaxf(sqrtf(sv), EPSN);
    }
    __syncthreads();

    // ---- top-K via 256-element bitonic sort, all 256 threads ----
    // key = (~monotone(score) << 32) | index  -> ascending sort gives
    // descending score, tie -> smallest index (jax.lax.top_k semantics).
    unsigned long long v;
    {
        const float s = s_scores[tid];
        unsigned u = __float_as_uint(s);
        unsigned f = (u & 0x80000000u) ? ~u : (u | 0x80000000u);
        unsigned kd = ~f;
        v = ((unsigned long long)kd << 32) | (unsigned)tid;
    }
    #pragma unroll
    for (unsigned k = 2; k <= 256; k <<= 1) {
        #pragma unroll
        for (unsigned j = k >> 1; j > 0; j >>= 1) {
            unsigned long long p;
            if (j >= 64) {
                s_key[tid] = v;
                __syncthreads();
                p = s_key[tid ^ j];
                __syncthreads();
            } else {
                p = __shfl_xor(v, (int)j, 64);
            }
            const bool up      = ((tid & k) == 0);
            const bool upper   = (tid & j) != 0;
            const bool takeMax = (up == upper);
            v = takeMax ? (v > p ? v : p) : (v < p ? v : p);
        }
    }

    // threads 0..31 (wave 0) hold the top-32 in rank order
    if (tid < KSEL) {
        const int idx = (int)(v & 0xFFFFFFFFu);
        s_kid[tid] = idx;
        out_kid [(size_t)bh * KSEL + tid] = (float)idx;
        out_mask[(size_t)bh * KSEL + tid] = am[(size_t)bh * SDIM + 1 + idx];
        const float sc = s_scores[idx];
        const float m  = __shfl(sc, 0, 64);      // rank-0 score = max
        const float e  = expf(sc - m);
        float sum = e;
        #pragma unroll
        for (int o = 16; o > 0; o >>= 1) sum += __shfl_xor(sum, o, 32);
        s_w[tid] = e / sum;
    }
    __syncthreads();

    // ---- output: gather txt rows, scale by w, add segment embedding ----
    const float* txtb = ne + ((size_t)bh * SDIM + 1) * DDIM;
    float* outb = out_terms + (size_t)bh * KSEL * DDIM;
    const int d4 = tid & 63;
    #pragma unroll
    for (int p = 0; p < 8; ++p) {
        const int k    = p * 4 + (tid >> 6);
        const int kidx = s_kid[k];
        const float wk = s_w[k];
        float4 x  = reinterpret_cast<const float4*>(txtb + (size_t)kidx * DDIM)[d4];
        float4 sg = s_seg[d4];
        float4 r;
        r.x = x.x * wk + sg.x;
        r.y = x.y * wk + sg.y;
        r.z = x.z * wk + sg.z;
        r.w = x.w * wk + sg.w;
        reinterpret_cast<float4*>(outb + (size_t)k * DDIM)[d4] = r;
    }
}

extern "C" void kernel_launch(void* const* d_in, const int* in_sizes, int n_in,
                              void* d_out, int out_size, void* d_ws, size_t ws_size,
                              hipStream_t stream) {
    const float* nse = (const float*)d_in[0];
    const float* ne  = (const float*)d_in[1];
    const float* ur  = (const float*)d_in[2];
    const float* am  = (const float*)d_in[4];
    const int*   rm  = (const int*)  d_in[5];
    const float* seg = (const float*)d_in[6];

    const int B = in_sizes[2] / DDIM;
    const int H = in_sizes[6] / DDIM;

    float* out = (float*)d_out;
    const size_t n_terms = (size_t)B * H * KSEL * DDIM;
    const size_t n_mask  = (size_t)B * H * KSEL;

    matching_reducer_kernel<<<dim3(B * H), dim3(256), 0, stream>>>(
        nse, ne, ur, am, rm, seg,
        out, out + n_terms, out + n_terms + n_mask, H);
}

// Round 6
// 32.679 us; speedup vs baseline: 1.9376x; 1.0141x over previous
//
#include <hip/hip_runtime.h>
#include <math.h>

#define KSEL 32
#define DDIM 256
#define SDIM 256
#define SM1  255
#define EPSN 1e-12f

__global__ __launch_bounds__(256) void matching_reducer_kernel(
    const float* __restrict__ nse,   // (B,H,S,D) news_selection_embedding
    const float* __restrict__ ne,    // (B,H,S,D) news_embedding
    const float* __restrict__ ur,    // (B,1,D)   user_repr
    const float* __restrict__ am,    // (B,H,S)   his_attn_mask
    const int*   __restrict__ rm,    // (B,H,S)   his_refined_mask
    const float* __restrict__ seg,   // (H,1,D)   segment_embedding
    float* __restrict__ out_terms,   // (B,H*K,D)
    float* __restrict__ out_mask,    // (B,H*K)
    float* __restrict__ out_kid,     // (B,H*K)   indices as float
    int H)
{
    const int bh   = blockIdx.x;
    const int b    = bh / H;
    const int h    = bh % H;
    const int tid  = threadIdx.x;
    const int lane = tid & 63;
    const int wave = tid >> 6;   // 0..3
    const int g    = tid >> 4;   // 16 groups of 16 lanes
    const int t    = tid & 15;

    __shared__ float  s_dot[256][17];   // per-row lane partials (pad 17)
    __shared__ float  s_ss[256][17];
    __shared__ float  s_scores[256];
    __shared__ int    s_rows[256];
    __shared__ unsigned long long s_key[256];
    __shared__ int    s_wbase[4];
    __shared__ int    s_nv;
    __shared__ int    s_kid[KSEL];
    __shared__ float  s_w[KSEL];
    __shared__ float4 s_seg[64];

    // ---- stage A loads FIRST: rows g and g+16 of the first 32 slots are
    //      ALWAYS valid (keep_k), addresses known at entry — issue before
    //      any mask/compaction work so HBM streams from cycle ~0 ----
    const float* selb = nse + ((size_t)bh * SDIM + 1) * DDIM;
    const float4* xa0 = reinterpret_cast<const float4*>(selb + (size_t)g * DDIM);
    const float4* xb0 = reinterpret_cast<const float4*>(selb + (size_t)(g + 16) * DDIM);
    float4 vA[4], vB[4];
    #pragma unroll
    for (int j = 0; j < 4; ++j) { vA[j] = xa0[t + 16 * j]; vB[j] = xb0[t + 16 * j]; }

    // q fragments: lane t holds q float4s {t, t+16, t+32, t+48}
    const float4* qv = reinterpret_cast<const float4*>(ur + (size_t)b * DDIM);
    float4 qf[4];
    #pragma unroll
    for (int j = 0; j < 4; ++j) qf[j] = qv[t + 16 * j];

    if (tid < 64) {
        s_seg[tid] = reinterpret_cast<const float4*>(seg + (size_t)h * DDIM)[tid];
    }
    s_scores[tid] = -INFINITY;

    // ---- validity + compaction: valid = refined_mask!=0 OR first-K slot ----
    const int* rmb = rm + (size_t)bh * SDIM + 1;
    const bool valid = (tid < SM1) && ((rmb[tid] != 0) || (tid < KSEL));
    const unsigned long long ball = __ballot(valid);
    if (lane == 0) s_wbase[wave] = __popcll(ball);

    float qq = 0.f;
    #pragma unroll
    for (int j = 0; j < 4; ++j)
        qq += qf[j].x * qf[j].x + qf[j].y * qf[j].y + qf[j].z * qf[j].z + qf[j].w * qf[j].w;
    #pragma unroll
    for (int o = 8; o > 0; o >>= 1) qq += __shfl_xor(qq, o, 16);
    const float inv_q = 1.0f / fmaxf(sqrtf(qq), EPSN);

    __syncthreads();
    if (tid == 0) {
        int acc = 0;
        #pragma unroll
        for (int w2 = 0; w2 < 4; ++w2) { int c = s_wbase[w2]; s_wbase[w2] = acc; acc += c; }
        s_nv = acc;
    }
    __syncthreads();
    if (valid) {
        const int off = __popcll(ball & ((1ull << lane) - 1ull));
        s_rows[s_wbase[wave] + off] = tid;   // note: s_rows[i]=i for i<32
    }

    // ---- stage A compute (loads long since in flight) ----
    {
        float dotA = 0.f, ssA = 0.f, dotB = 0.f, ssB = 0.f;
        #pragma unroll
        for (int j = 0; j < 4; ++j) {
            dotA += vA[j].x * qf[j].x + vA[j].y * qf[j].y + vA[j].z * qf[j].z + vA[j].w * qf[j].w;
            ssA  += vA[j].x * vA[j].x + vA[j].y * vA[j].y + vA[j].z * vA[j].z + vA[j].w * vA[j].w;
            dotB += vB[j].x * qf[j].x + vB[j].y * qf[j].y + vB[j].z * qf[j].z + vB[j].w * qf[j].w;
            ssB  += vB[j].x * vB[j].x + vB[j].y * vB[j].y + vB[j].z * vB[j].z + vB[j].w * vB[j].w;
        }
        s_dot[g][t]      = dotA;
        s_ss [g][t]      = ssA;
        s_dot[g + 16][t] = dotB;
        s_ss [g + 16][t] = ssB;
    }
    __syncthreads();

    // ---- stage B: compacted valid rows >= 32, FOUR rows in flight/group ----
    const int nv = s_nv;
    for (int i = 32 + g; i < nv; i += 64) {
        const bool h1 = (i + 16) < nv;
        const bool h2 = (i + 32) < nv;
        const bool h3 = (i + 48) < nv;
        const int r0 = s_rows[i];
        const int r1 = h1 ? s_rows[i + 16] : r0;
        const int r2 = h2 ? s_rows[i + 32] : r0;
        const int r3 = h3 ? s_rows[i + 48] : r0;
        const float4* x0 = reinterpret_cast<const float4*>(selb + (size_t)r0 * DDIM);
        const float4* x1 = reinterpret_cast<const float4*>(selb + (size_t)r1 * DDIM);
        const float4* x2 = reinterpret_cast<const float4*>(selb + (size_t)r2 * DDIM);
        const float4* x3 = reinterpret_cast<const float4*>(selb + (size_t)r3 * DDIM);
        float4 v0[4], v1[4], v2[4], v3[4];
        #pragma unroll
        for (int j = 0; j < 4; ++j) {
            v0[j] = x0[t + 16 * j];
            v1[j] = x1[t + 16 * j];
            v2[j] = x2[t + 16 * j];
            v3[j] = x3[t + 16 * j];
        }
        float d0 = 0.f, s0 = 0.f, d1 = 0.f, s1 = 0.f;
        float d2 = 0.f, s2 = 0.f, d3 = 0.f, s3 = 0.f;
        #pragma unroll
        for (int j = 0; j < 4; ++j) {
            d0 += v0[j].x * qf[j].x + v0[j].y * qf[j].y + v0[j].z * qf[j].z + v0[j].w * qf[j].w;
            s0 += v0[j].x * v0[j].x + v0[j].y * v0[j].y + v0[j].z * v0[j].z + v0[j].w * v0[j].w;
            d1 += v1[j].x * qf[j].x + v1[j].y * qf[j].y + v1[j].z * qf[j].z + v1[j].w * qf[j].w;
            s1 += v1[j].x * v1[j].x + v1[j].y * v1[j].y + v1[j].z * v1[j].z + v1[j].w * v1[j].w;
            d2 += v2[j].x * qf[j].x + v2[j].y * qf[j].y + v2[j].z * qf[j].z + v2[j].w * qf[j].w;
            s2 += v2[j].x * v2[j].x + v2[j].y * v2[j].y + v2[j].z * v2[j].z + v2[j].w * v2[j].w;
            d3 += v3[j].x * qf[j].x + v3[j].y * qf[j].y + v3[j].z * qf[j].z + v3[j].w * qf[j].w;
            s3 += v3[j].x * v3[j].x + v3[j].y * v3[j].y + v3[j].z * v3[j].z + v3[j].w * v3[j].w;
        }
        s_dot[r0][t] = d0; s_ss[r0][t] = s0;
        if (h1) { s_dot[r1][t] = d1; s_ss[r1][t] = s1; }
        if (h2) { s_dot[r2][t] = d2; s_ss[r2][t] = s2; }
        if (h3) { s_dot[r3][t] = d3; s_ss[r3][t] = s3; }
    }
    __syncthreads();

    // ---- per-row partial reduce: thread tid owns row tid ----
    if (valid) {
        float dv = 0.f, sv = 0.f;
        #pragma unroll
        for (int j = 0; j < 16; ++j) { dv += s_dot[tid][j]; sv += s_ss[tid][j]; }
        s_scores[tid] = dv * inv_q / fmaxf(sqrtf(sv), EPSN);
    }
    __syncthreads();

    // ---- top-K via 256-element bitonic sort, all 256 threads ----
    unsigned long long v;
    {
        const float s = s_scores[tid];
        unsigned u = __float_as_uint(s);
        unsigned f = (u & 0x80000000u) ? ~u : (u | 0x80000000u);
        unsigned kd = ~f;
        v = ((unsigned long long)kd << 32) | (unsigned)tid;
    }
    #pragma unroll
    for (unsigned k = 2; k <= 256; k <<= 1) {
        #pragma unroll
        for (unsigned j = k >> 1; j > 0; j >>= 1) {
            unsigned long long p;
            if (j >= 64) {
                s_key[tid] = v;
                __syncthreads();
                p = s_key[tid ^ j];
                __syncthreads();
            } else {
                p = __shfl_xor(v, (int)j, 64);
            }
            const bool up      = ((tid & k) == 0);
            const bool upper   = (tid & j) != 0;
            const bool takeMax = (up == upper);
            v = takeMax ? (v > p ? v : p) : (v < p ? v : p);
        }
    }

    // threads 0..31 hold the top-32 in rank order
    if (tid < KSEL) {
        const int idx = (int)(v & 0xFFFFFFFFu);
        s_kid[tid] = idx;
        out_kid [(size_t)bh * KSEL + tid] = (float)idx;
        out_mask[(size_t)bh * KSEL + tid] = am[(size_t)bh * SDIM + 1 + idx];
        const float sc = s_scores[idx];
        const float m  = __shfl(sc, 0, 64);      // rank-0 score = max
        const float e  = expf(sc - m);
        float sum = e;
        #pragma unroll
        for (int o = 16; o > 0; o >>= 1) sum += __shfl_xor(sum, o, 32);
        s_w[tid] = e / sum;
    }
    __syncthreads();

    // ---- output: gather txt rows, scale by w, add segment embedding ----
    const float* txtb = ne + ((size_t)bh * SDIM + 1) * DDIM;
    float* outb = out_terms + (size_t)bh * KSEL * DDIM;
    const int d4 = tid & 63;
    #pragma unroll
    for (int p = 0; p < 8; ++p) {
        const int k    = p * 4 + (tid >> 6);
        const int kidx = s_kid[k];
        const float wk = s_w[k];
        float4 x  = reinterpret_cast<const float4*>(txtb + (size_t)kidx * DDIM)[d4];
        float4 sg = s_seg[d4];
        float4 r;
        r.x = x.x * wk + sg.x;
        r.y = x.y * wk + sg.y;
        r.z = x.z * wk + sg.z;
        r.w = x.w * wk + sg.w;
        reinterpret_cast<float4*>(outb + (size_t)k * DDIM)[d4] = r;
    }
}

extern "C" void kernel_launch(void* const* d_in, const int* in_sizes, int n_in,
                              void* d_out, int out_size, void* d_ws, size_t ws_size,
                              hipStream_t stream) {
    const float* nse = (const float*)d_in[0];
    const float* ne  = (const float*)d_in[1];
    const float* ur  = (const float*)d_in[2];
    const float* am  = (const float*)d_in[4];
    const int*   rm  = (const int*)  d_in[5];
    const float* seg = (const float*)d_in[6];

    const int B = in_sizes[2] / DDIM;
    const int H = in_sizes[6] / DDIM;

    float* out = (float*)d_out;
    const size_t n_terms = (size_t)B * H * KSEL * DDIM;
    const size_t n_mask  = (size_t)B * H * KSEL;

    matching_reducer_kernel<<<dim3(B * H), dim3(256), 0, stream>>>(
        nse, ne, ur, am, rm, seg,
        out, out + n_terms, out + n_terms + n_mask, H);
}